// Round 1
// 244.058 us; speedup vs baseline: 1.0103x; 1.0103x over previous
//
#include <hip/hip_runtime.h>
#include <stdint.h>

#define HW 4096
#define CCH 256
#define BPL (CCH * HW)          // per-batch plane elems
#define LSTR 264                // LDS Bs row stride in shorts (256+8 pad; 528B = 16B-aligned)
#define TSTR 76                 // dw tile row stride in floats (304B = 12 banks mod 32: odd
                                //  multiple of 4 -> rows tile all banks; 72 was 0 mod 32 -> 8-way)

typedef __attribute__((ext_vector_type(8))) short short8;
typedef __attribute__((ext_vector_type(4))) float floatx4;
typedef unsigned short ushort_t;

__device__ inline ushort_t f2bf(float f) {
    union { float f; unsigned int u; } v; v.f = f;
    unsigned int r = v.u + 0x7FFFu + ((v.u >> 16) & 1u);   // RNE
    return (ushort_t)(r >> 16);
}
__device__ inline float bf2f(ushort_t u) {
    union { unsigned int u; float f; } v; v.u = ((unsigned int)u) << 16;
    return v.f;
}

// MFMA A-fragment packed weight layout: for 16x16x32 bf16, lane (quad*16+L) of
// wave w holds A[row=cout][k] with cout = w*64 + mt*16 + L, k = kt*32 + quad*8 + e.
// dst = ((((w*8 + kt)*4 + mt)*64 + quad*16 + L)*8 + e  -> each wave fragment load
// is 64 lanes x 16B CONTIGUOUS (1KB) instead of 16B every 512B (64 L2 lines/load).
__device__ inline int wpack(int c, int t) {
    const int w  = c >> 6, mt = (c >> 4) & 3, L = c & 15;
    const int kt = t >> 5, quad = (t >> 3) & 3, e = t & 7;
    return ((((w * 8 + kt) * 4 + mt) * 64 + quad * 16 + L) * 8 + e);
}

// ---------------------------------------------------------------------------
// prep: weights->bf16 (fragment-packed), combined dw 9x9 (chunked layout),
// folded BN params. WcP[c][128]: slots 0..44 = dy 0..4 (dy*9+dx), 64..99 = dy 5..8.
__global__ void prep_kernel(
    const float* __restrict__ pre_w, const float* __restrict__ pw_w, const float* __restrict__ post_w,
    const float* __restrict__ g1, const float* __restrict__ b1, const float* __restrict__ m1, const float* __restrict__ v1,
    const float* __restrict__ g2, const float* __restrict__ b2, const float* __restrict__ m2, const float* __restrict__ v2,
    const float* __restrict__ g3, const float* __restrict__ b3, const float* __restrict__ m3, const float* __restrict__ v3,
    const float* __restrict__ w3d, const float* __restrict__ b3d,
    const float* __restrict__ w5d, const float* __restrict__ b5d,
    const float* __restrict__ w7d, const float* __restrict__ b7d,
    const float* __restrict__ w9d, const float* __restrict__ b9d,
    ushort_t* __restrict__ w1b, ushort_t* __restrict__ w2b, ushort_t* __restrict__ w3b,
    float* __restrict__ WcP, float* __restrict__ biasc,
    float* __restrict__ sc1, float* __restrict__ sh1,
    float* __restrict__ sc2, float* __restrict__ sh2,
    float* __restrict__ sc3, float* __restrict__ sh3)
{
    int c = blockIdx.x, t = threadIdx.x;
    const int p = wpack(c, t);
    w1b[p] = f2bf(pre_w[c * 256 + t]);
    w2b[p] = f2bf(pw_w[c * 256 + t]);
    w3b[p] = f2bf(post_w[c * 256 + t]);
    if (t < 128) {
        float val = 0.f;
        int dy = -1, dx = 0;
        if (t < 45) { dy = t / 9; dx = t % 9; }
        else if (t >= 64 && t < 100) { int i = t - 64; dy = 5 + i / 9; dx = i % 9; }
        if (dy >= 0) {
            val = w9d[c * 81 + dy * 9 + dx];
            if (dy >= 1 && dy <= 7 && dx >= 1 && dx <= 7) val += w7d[c * 49 + (dy - 1) * 7 + (dx - 1)];
            if (dy >= 2 && dy <= 6 && dx >= 2 && dx <= 6) val += w5d[c * 25 + (dy - 2) * 5 + (dx - 2)];
            if (dy >= 3 && dy <= 5 && dx >= 3 && dx <= 5) val += w3d[c * 9 + (dy - 3) * 3 + (dx - 3)];
            if (dy == 4 && dx == 4) val += 1.0f;  // identity branch
        }
        WcP[c * 128 + t] = val;
    }
    if (t == 128) { float s = g1[c] * rsqrtf(v1[c] + 1e-5f); sc1[c] = s; sh1[c] = b1[c] - m1[c] * s; }
    if (t == 129) { float s = g2[c] * rsqrtf(v2[c] + 1e-5f); sc2[c] = s; sh2[c] = b2[c] - m2[c] * s; }
    if (t == 130) { float s = g3[c] * rsqrtf(v3[c] + 1e-5f); sc3[c] = s; sh3[c] = b3[c] - m3[c] * s; }
    if (t == 131) biasc[c] = b3d[c] + b5d[c] + b7d[c] + b9d[c];
}

// ---------------------------------------------------------------------------
// LDS-staged MFMA 1x1 conv(s) on a 128-px tile, all 256 cout, K=256.
// Staging transposes the NCHW input tile into Bs[px][ch] bf16 (fuses the
// transpose kernels). Wave w computes cout 64w..64w+63 (4 m-tiles x 8 n-tiles).
// MODE 0: in fp32 NCHW -> GEMM(wA)+bnA+relu -> bf16 NCHW       (conv1)
// MODE 1: in bf16 NCHW -> GEMM(wA)+bnA+relu -> t in LDS ->
//         GEMM(wB)+bnB+relu -> fp32 NCHW                       (conv2+conv3)
template <int MODE>
__global__ __launch_bounds__(256, 2) void conv_tile(
    const void* __restrict__ inp,
    const ushort_t* __restrict__ wA, const float* __restrict__ scA, const float* __restrict__ shA,
    const ushort_t* __restrict__ wB, const float* __restrict__ scB, const float* __restrict__ shB,
    void* __restrict__ outp)
{
    __shared__ __align__(16) ushort_t Bs[128 * LSTR];   // 67.6 KB
    const int tid = threadIdx.x;
    const int P0 = blockIdx.x * 128;          // global pixel base (never crosses batch)
    const int b = P0 >> 12, hw0 = P0 & 4095;
    unsigned int* Bsd = (unsigned int*)Bs;

    // ---- stage input tile [256 ch][128 px] -> Bs[px][ch] (ch-pairs packed as dwords)
    {
        const int c2 = tid & 127, ph = tid >> 7, px0 = ph * 64;
        if (MODE == 0) {
            const float* s0 = (const float*)inp + (size_t)b * BPL + (size_t)(2 * c2) * HW + hw0 + px0;
            const float* s1 = s0 + HW;
#pragma unroll
            for (int i = 0; i < 16; i++) {
                float4 v0 = *(const float4*)(s0 + 4 * i);
                float4 v1 = *(const float4*)(s1 + 4 * i);
                const int px = px0 + 4 * i;
                Bsd[(px + 0) * (LSTR / 2) + c2] = (unsigned)f2bf(v0.x) | ((unsigned)f2bf(v1.x) << 16);
                Bsd[(px + 1) * (LSTR / 2) + c2] = (unsigned)f2bf(v0.y) | ((unsigned)f2bf(v1.y) << 16);
                Bsd[(px + 2) * (LSTR / 2) + c2] = (unsigned)f2bf(v0.z) | ((unsigned)f2bf(v1.z) << 16);
                Bsd[(px + 3) * (LSTR / 2) + c2] = (unsigned)f2bf(v0.w) | ((unsigned)f2bf(v1.w) << 16);
            }
        } else {
            const ushort_t* s0 = (const ushort_t*)inp + (size_t)b * BPL + (size_t)(2 * c2) * HW + hw0 + px0;
            const ushort_t* s1 = s0 + HW;
#pragma unroll
            for (int i = 0; i < 8; i++) {
                union { uint4 v; ushort_t u[8]; } r0, r1;
                r0.v = *(const uint4*)(s0 + 8 * i);
                r1.v = *(const uint4*)(s1 + 8 * i);
                const int px = px0 + 8 * i;
#pragma unroll
                for (int j = 0; j < 8; j++)
                    Bsd[(px + j) * (LSTR / 2) + c2] = (unsigned)r0.u[j] | ((unsigned)r1.u[j] << 16);
            }
        }
    }
    __syncthreads();

    const int wave = tid >> 6, lane = tid & 63, quad = lane >> 4, L = lane & 15;
    const int coutw = wave * 64;

    floatx4 acc[4][8];

    // GEMM over K=256 (8 chunks of 32): A from global in fragment-packed order
    // (each load = 1KB contiguous per wave, L2-hot, prefetched one chunk ahead),
    // B from LDS.
    auto run_gemm = [&](const ushort_t* W) {
#pragma unroll
        for (int mt = 0; mt < 4; mt++)
#pragma unroll
            for (int nt = 0; nt < 8; nt++) acc[mt][nt] = (floatx4){0.f, 0.f, 0.f, 0.f};
        const ushort_t* Ab = W + (size_t)wave * 16384 + (size_t)lane * 8;
        short8 Ac[4], An[4];
#pragma unroll
        for (int mt = 0; mt < 4; mt++) Ac[mt] = *(const short8*)(Ab + mt * 512);
#pragma unroll
        for (int kt = 0; kt < 8; kt++) {
            if (kt < 7) {
#pragma unroll
                for (int mt = 0; mt < 4; mt++)
                    An[mt] = *(const short8*)(Ab + ((kt + 1) * 4 + mt) * 512);
            }
            short8 Bf[8];
#pragma unroll
            for (int nt = 0; nt < 8; nt++)
                Bf[nt] = *(const short8*)&Bs[(nt * 16 + L) * LSTR + kt * 32 + quad * 8];
#pragma unroll
            for (int mt = 0; mt < 4; mt++)
#pragma unroll
                for (int nt = 0; nt < 8; nt++)
                    acc[mt][nt] = __builtin_amdgcn_mfma_f32_16x16x32_bf16(
                        Ac[mt], Bf[nt], acc[mt][nt], 0, 0, 0);
            if (kt < 7) {
#pragma unroll
                for (int mt = 0; mt < 4; mt++) Ac[mt] = An[mt];
            }
        }
    };

    run_gemm(wA);

    if (MODE == 0) {
        // epilogue: bnA + relu -> bf16 NCHW
        ushort_t* outb = (ushort_t*)outp + (size_t)b * BPL + hw0;
#pragma unroll
        for (int mt = 0; mt < 4; mt++) {
#pragma unroll
            for (int r = 0; r < 4; r++) {
                const int cout = coutw + mt * 16 + quad * 4 + r;
                const float s = scA[cout], h0 = shA[cout];
#pragma unroll
                for (int nt = 0; nt < 8; nt++)
                    outb[(size_t)cout * HW + nt * 16 + L] =
                        f2bf(fmaxf(fmaf(acc[mt][nt][r], s, h0), 0.f));
            }
        }
    } else {
        // t = relu(bnA(.)) -> back into Bs (in-place; s fully consumed)
        __syncthreads();
#pragma unroll
        for (int mt = 0; mt < 4; mt++) {
            const int cout0 = coutw + mt * 16 + quad * 4;
            float sc4[4], sh4[4];
#pragma unroll
            for (int r = 0; r < 4; r++) { sc4[r] = scA[cout0 + r]; sh4[r] = shA[cout0 + r]; }
#pragma unroll
            for (int nt = 0; nt < 8; nt++) {
                const int px = nt * 16 + L;
                ushort4 pk;
                pk.x = f2bf(fmaxf(fmaf(acc[mt][nt][0], sc4[0], sh4[0]), 0.f));
                pk.y = f2bf(fmaxf(fmaf(acc[mt][nt][1], sc4[1], sh4[1]), 0.f));
                pk.z = f2bf(fmaxf(fmaf(acc[mt][nt][2], sc4[2], sh4[2]), 0.f));
                pk.w = f2bf(fmaxf(fmaf(acc[mt][nt][3], sc4[3], sh4[3]), 0.f));
                *(ushort4*)&Bs[px * LSTR + cout0] = pk;
            }
        }
        __syncthreads();
        run_gemm(wB);
        // epilogue: bnB + relu -> fp32 NCHW
        float* outb = (float*)outp + (size_t)b * BPL + hw0;
#pragma unroll
        for (int mt = 0; mt < 4; mt++) {
#pragma unroll
            for (int r = 0; r < 4; r++) {
                const int cout = coutw + mt * 16 + quad * 4 + r;
                const float s = scB[cout], h0 = shB[cout];
#pragma unroll
                for (int nt = 0; nt < 8; nt++)
                    outb[(size_t)cout * HW + nt * 16 + L] =
                        fmaxf(fmaf(acc[mt][nt][r], s, h0), 0.f);
            }
        }
    }
}

// ---------------------------------------------------------------------------
// Combined 9x9 depthwise (+identity, +summed bias), bf16 NCHW in/out.
// One block per (b,c) plane; 72-row x TSTR-stride fp32 LDS tile; 2 weight chunks.
// TSTR=76 (12 banks/row): win ds_read_b128 spans tile all 32 banks per 8 lanes
// (stride 72 was 0 mod 32 banks -> 8-way conflict, 1.3e7 conflict-cycles/dispatch).
// launch_bounds min-waves=3 -> VGPR cap ~170: NO SPILLS (R4's (256,4) spilled).
__global__ __launch_bounds__(256, 3) void dw_kernel(
    const ushort_t* __restrict__ h, const float* __restrict__ WcP,
    const float* __restrict__ biasc, ushort_t* __restrict__ out)
{
    const int bcp = blockIdx.x, c = bcp & 255;
    const size_t plane = (size_t)bcp * HW;
    __shared__ float tile[72 * TSTR];
    const int tid = threadIdx.x;

    // zero halo borders (280 float4 regions, disjoint from interior rows 4..67)
    for (int f = tid; f < 280; f += 256) {
        int row, col4;
        if (f < 152) { int r = f / 19; row = (r < 4) ? r : r + 64; col4 = (f % 19) * 4; }
        else { int f2 = f - 152; row = 4 + (f2 >> 1); col4 = (f2 & 1) ? 68 : 0; }
        *(float4*)&tile[row * TSTR + col4] = (float4){0.f, 0.f, 0.f, 0.f};
    }
    // interior: thread loads 32 contiguous bytes (16 px) of row r.
    // lane->(r,q) map: r steps with lane&15 so consecutive lanes step 12 banks
    // (perfect 32-bank tiling); global read set is identical, just lane-permuted.
    {
        const int lane = tid & 63, wv = tid >> 6;
        const int r = (wv << 4) | (lane & 15);   // 0..63
        const int q = lane >> 4;                 // 0..3
        const ushort_t* src = h + plane + r * 64 + q * 16;
        union { uint4 v; ushort_t u[8]; } a, bq;
        a.v  = *(const uint4*)src;
        bq.v = *(const uint4*)(src + 8);
        float* drow = &tile[(r + 4) * TSTR + 4 + q * 16];
        float4 t0, t1;
        t0.x = bf2f(a.u[0]); t0.y = bf2f(a.u[1]); t0.z = bf2f(a.u[2]); t0.w = bf2f(a.u[3]);
        t1.x = bf2f(a.u[4]); t1.y = bf2f(a.u[5]); t1.z = bf2f(a.u[6]); t1.w = bf2f(a.u[7]);
        *(float4*)&drow[0] = t0; *(float4*)&drow[4] = t1;
        t0.x = bf2f(bq.u[0]); t0.y = bf2f(bq.u[1]); t0.z = bf2f(bq.u[2]); t0.w = bf2f(bq.u[3]);
        t1.x = bf2f(bq.u[4]); t1.y = bf2f(bq.u[5]); t1.z = bf2f(bq.u[6]); t1.w = bf2f(bq.u[7]);
        *(float4*)&drow[8] = t0; *(float4*)&drow[12] = t1;
    }
    __syncthreads();

    const int tx = tid & 15, ty = tid >> 4;
    const int x0 = tx * 4, y0 = ty * 4;
    float acc[4][4];
#pragma unroll
    for (int i = 0; i < 4; i++)
#pragma unroll
        for (int j = 0; j < 4; j++) acc[i][j] = 0.f;

    const float* wp = WcP + c * 128;
    float wr[48];

    // chunk A: dy 0..4 (45 weights), rows y0+0..7
#pragma unroll
    for (int i = 0; i < 12; i++) *(float4*)&wr[4 * i] = *(const float4*)(wp + 4 * i);
#pragma unroll
    for (int r6 = 0; r6 < 8; r6++) {
        const float* row = &tile[(y0 + r6) * TSTR + x0];
        float win[12];
        *(float4*)&win[0] = *(const float4*)&row[0];
        *(float4*)&win[4] = *(const float4*)&row[4];
        *(float4*)&win[8] = *(const float4*)&row[8];
#pragma unroll
        for (int yy = 0; yy < 4; yy++) {
            const int d = r6 - yy;
            if (d >= 0 && d <= 4) {
#pragma unroll
                for (int t = 0; t < 9; t++)
#pragma unroll
                    for (int j = 0; j < 4; j++)
                        acc[yy][j] = fmaf(wr[d * 9 + t], win[j + t], acc[yy][j]);
            }
        }
    }
    // chunk B: dy 5..8 (36 weights), rows y0+5..11
#pragma unroll
    for (int i = 0; i < 9; i++) *(float4*)&wr[4 * i] = *(const float4*)(wp + 64 + 4 * i);
#pragma unroll
    for (int r6 = 5; r6 < 12; r6++) {
        const float* row = &tile[(y0 + r6) * TSTR + x0];
        float win[12];
        *(float4*)&win[0] = *(const float4*)&row[0];
        *(float4*)&win[4] = *(const float4*)&row[4];
        *(float4*)&win[8] = *(const float4*)&row[8];
#pragma unroll
        for (int yy = 0; yy < 4; yy++) {
            const int d = r6 - yy;
            if (d >= 5 && d <= 8) {
#pragma unroll
                for (int t = 0; t < 9; t++)
#pragma unroll
                    for (int j = 0; j < 4; j++)
                        acc[yy][j] = fmaf(wr[(d - 5) * 9 + t], win[j + t], acc[yy][j]);
            }
        }
    }

    const float bb = biasc[c];
#pragma unroll
    for (int yy = 0; yy < 4; yy++) {
        ushort4 o;
        o.x = f2bf(acc[yy][0] + bb);
        o.y = f2bf(acc[yy][1] + bb);
        o.z = f2bf(acc[yy][2] + bb);
        o.w = f2bf(acc[yy][3] + bb);
        *(ushort4*)&out[plane + (size_t)(y0 + yy) * 64 + x0] = o;
    }
}

// ---------------------------------------------------------------------------
extern "C" void kernel_launch(void* const* d_in, const int* in_sizes, int n_in,
                              void* d_out, int out_size, void* d_ws, size_t ws_size,
                              hipStream_t stream) {
    const float* x     = (const float*)d_in[0];
    const float* pre_w = (const float*)d_in[1];
    const float* bn1g  = (const float*)d_in[2];
    const float* bn1b  = (const float*)d_in[3];
    const float* bn1m  = (const float*)d_in[4];
    const float* bn1v  = (const float*)d_in[5];
    const float* dw3w  = (const float*)d_in[6];
    const float* dw3b  = (const float*)d_in[7];
    const float* dw5w  = (const float*)d_in[8];
    const float* dw5b  = (const float*)d_in[9];
    const float* dw7w  = (const float*)d_in[10];
    const float* dw7b  = (const float*)d_in[11];
    const float* dw9w  = (const float*)d_in[12];
    const float* dw9b  = (const float*)d_in[13];
    const float* pww   = (const float*)d_in[14];
    const float* bn2g  = (const float*)d_in[15];
    const float* bn2b  = (const float*)d_in[16];
    const float* bn2m  = (const float*)d_in[17];
    const float* bn2v  = (const float*)d_in[18];
    const float* postw = (const float*)d_in[19];
    const float* bn3g  = (const float*)d_in[20];
    const float* bn3b  = (const float*)d_in[21];
    const float* bn3m  = (const float*)d_in[22];
    const float* bn3v  = (const float*)d_in[23];

    // Buffers:
    //   h (bf16, 32 MiB)  -> d_out storage (dead before final fp32 write)
    //   s (bf16, 32 MiB)  -> ws[0:32Mi]
    //   aux               -> ws + 33 MiB
    char* wsb = (char*)d_ws;
    ushort_t* sbuf = (ushort_t*)wsb;
    ushort_t* hbuf = (ushort_t*)d_out;
    char* aux = wsb + (size_t)33 * 1024 * 1024;
    ushort_t* w1b = (ushort_t*)aux;
    ushort_t* w2b = w1b + 65536;
    ushort_t* w3b = w2b + 65536;
    float* WcP   = (float*)(w3b + 65536);      // 256*128 fp32
    float* biasc = WcP + 256 * 128;
    float* sc1 = biasc + 256;  float* sh1 = sc1 + 256;
    float* sc2 = sh1 + 256;    float* sh2 = sc2 + 256;
    float* sc3 = sh2 + 256;    float* sh3 = sc3 + 256;

    prep_kernel<<<256, 256, 0, stream>>>(
        pre_w, pww, postw,
        bn1g, bn1b, bn1m, bn1v, bn2g, bn2b, bn2m, bn2v, bn3g, bn3b, bn3m, bn3v,
        dw3w, dw3b, dw5w, dw5b, dw7w, dw7b, dw9w, dw9b,
        w1b, w2b, w3b, WcP, biasc, sc1, sh1, sc2, sh2, sc3, sh3);

    // conv1: x fp32 -> h bf16 NCHW (in d_out storage)
    conv_tile<0><<<512, 256, 0, stream>>>(x, w1b, sc1, sh1,
                                          nullptr, nullptr, nullptr, hbuf);
    // dw: h -> s bf16 NCHW (in ws)
    dw_kernel<<<16 * CCH, 256, 0, stream>>>(hbuf, WcP, biasc, sbuf);
    // conv2+conv3 fused: s -> out fp32 NCHW (d_out; h dead)
    conv_tile<1><<<512, 256, 0, stream>>>(sbuf, w2b, sc2, sh2,
                                          w3b, sc3, sh3, (float*)d_out);
}

// Round 2
// 227.655 us; speedup vs baseline: 1.0831x; 1.0721x over previous
//
#include <hip/hip_runtime.h>
#include <stdint.h>

#define HW 4096
#define CCH 256
#define BPL (CCH * HW)          // per-batch plane elems
#define LSTR 264                // LDS Bs row stride in shorts (256+8 pad; 528B = 16B-aligned)
#define DSTR 84                 // dw bf16 tile row stride in shorts (168B): quarter-wave b64
                                //  reads span one contiguous 128B wrap -> conflict-free;
                                //  staging writes (5r+4q mod 16) tile all bank-pairs.

typedef __attribute__((ext_vector_type(8))) short short8;
typedef __attribute__((ext_vector_type(4))) float floatx4;
typedef unsigned short ushort_t;

__device__ inline ushort_t f2bf(float f) {
    union { float f; unsigned int u; } v; v.f = f;
    unsigned int r = v.u + 0x7FFFu + ((v.u >> 16) & 1u);   // RNE
    return (ushort_t)(r >> 16);
}
// unpack a dword holding 2 bf16 (little-endian: low short = lower col) to 2 floats
__device__ inline void up2(unsigned int d, float* w) {
    union { unsigned int u; float f; } lo, hi;
    lo.u = d << 16; hi.u = d & 0xffff0000u;
    w[0] = lo.f; w[1] = hi.f;
}

// MFMA A-fragment packed weight layout: for 16x16x32 bf16, lane (quad*16+L) of
// wave w holds A[row=cout][k] with cout = w*64 + mt*16 + L, k = kt*32 + quad*8 + e.
// dst = ((((w*8 + kt)*4 + mt)*64 + quad*16 + L)*8 + e  -> each wave fragment load
// is 64 lanes x 16B CONTIGUOUS (1KB) instead of 16B every 512B (64 L2 lines/load).
// [R1 post-mortem: this packing was worth ~14 us across the two conv dispatches.]
__device__ inline int wpack(int c, int t) {
    const int w  = c >> 6, mt = (c >> 4) & 3, L = c & 15;
    const int kt = t >> 5, quad = (t >> 3) & 3, e = t & 7;
    return ((((w * 8 + kt) * 4 + mt) * 64 + quad * 16 + L) * 8 + e);
}

// ---------------------------------------------------------------------------
// prep: weights->bf16 (fragment-packed), combined dw 9x9 (chunked layout),
// folded BN params. WcP[c][128]: slots 0..44 = dy 0..4 (dy*9+dx), 64..99 = dy 5..8.
__global__ void prep_kernel(
    const float* __restrict__ pre_w, const float* __restrict__ pw_w, const float* __restrict__ post_w,
    const float* __restrict__ g1, const float* __restrict__ b1, const float* __restrict__ m1, const float* __restrict__ v1,
    const float* __restrict__ g2, const float* __restrict__ b2, const float* __restrict__ m2, const float* __restrict__ v2,
    const float* __restrict__ g3, const float* __restrict__ b3, const float* __restrict__ m3, const float* __restrict__ v3,
    const float* __restrict__ w3d, const float* __restrict__ b3d,
    const float* __restrict__ w5d, const float* __restrict__ b5d,
    const float* __restrict__ w7d, const float* __restrict__ b7d,
    const float* __restrict__ w9d, const float* __restrict__ b9d,
    ushort_t* __restrict__ w1b, ushort_t* __restrict__ w2b, ushort_t* __restrict__ w3b,
    float* __restrict__ WcP, float* __restrict__ biasc,
    float* __restrict__ sc1, float* __restrict__ sh1,
    float* __restrict__ sc2, float* __restrict__ sh2,
    float* __restrict__ sc3, float* __restrict__ sh3)
{
    int c = blockIdx.x, t = threadIdx.x;
    const int p = wpack(c, t);
    w1b[p] = f2bf(pre_w[c * 256 + t]);
    w2b[p] = f2bf(pw_w[c * 256 + t]);
    w3b[p] = f2bf(post_w[c * 256 + t]);
    if (t < 128) {
        float val = 0.f;
        int dy = -1, dx = 0;
        if (t < 45) { dy = t / 9; dx = t % 9; }
        else if (t >= 64 && t < 100) { int i = t - 64; dy = 5 + i / 9; dx = i % 9; }
        if (dy >= 0) {
            val = w9d[c * 81 + dy * 9 + dx];
            if (dy >= 1 && dy <= 7 && dx >= 1 && dx <= 7) val += w7d[c * 49 + (dy - 1) * 7 + (dx - 1)];
            if (dy >= 2 && dy <= 6 && dx >= 2 && dx <= 6) val += w5d[c * 25 + (dy - 2) * 5 + (dx - 2)];
            if (dy >= 3 && dy <= 5 && dx >= 3 && dx <= 5) val += w3d[c * 9 + (dy - 3) * 3 + (dx - 3)];
            if (dy == 4 && dx == 4) val += 1.0f;  // identity branch
        }
        WcP[c * 128 + t] = val;
    }
    if (t == 128) { float s = g1[c] * rsqrtf(v1[c] + 1e-5f); sc1[c] = s; sh1[c] = b1[c] - m1[c] * s; }
    if (t == 129) { float s = g2[c] * rsqrtf(v2[c] + 1e-5f); sc2[c] = s; sh2[c] = b2[c] - m2[c] * s; }
    if (t == 130) { float s = g3[c] * rsqrtf(v3[c] + 1e-5f); sc3[c] = s; sh3[c] = b3[c] - m3[c] * s; }
    if (t == 131) biasc[c] = b3d[c] + b5d[c] + b7d[c] + b9d[c];
}

// ---------------------------------------------------------------------------
// LDS-staged MFMA 1x1 conv(s) on a 128-px tile, all 256 cout, K=256.
// Staging transposes the NCHW input tile into Bs[px][ch] bf16 (fuses the
// transpose kernels). Wave w computes cout 64w..64w+63 (4 m-tiles x 8 n-tiles).
// MODE 0: in fp32 NCHW -> GEMM(wA)+bnA+relu -> bf16 NCHW       (conv1)
// MODE 1: in bf16 NCHW -> GEMM(wA)+bnA+relu -> t in LDS ->
//         GEMM(wB)+bnB+relu -> fp32 NCHW                       (conv2+conv3)
template <int MODE>
__global__ __launch_bounds__(256, 2) void conv_tile(
    const void* __restrict__ inp,
    const ushort_t* __restrict__ wA, const float* __restrict__ scA, const float* __restrict__ shA,
    const ushort_t* __restrict__ wB, const float* __restrict__ scB, const float* __restrict__ shB,
    void* __restrict__ outp)
{
    __shared__ __align__(16) ushort_t Bs[128 * LSTR];   // 67.6 KB
    const int tid = threadIdx.x;
    const int P0 = blockIdx.x * 128;          // global pixel base (never crosses batch)
    const int b = P0 >> 12, hw0 = P0 & 4095;
    unsigned int* Bsd = (unsigned int*)Bs;

    // ---- stage input tile [256 ch][128 px] -> Bs[px][ch] (ch-pairs packed as dwords)
    {
        const int c2 = tid & 127, ph = tid >> 7, px0 = ph * 64;
        if (MODE == 0) {
            const float* s0 = (const float*)inp + (size_t)b * BPL + (size_t)(2 * c2) * HW + hw0 + px0;
            const float* s1 = s0 + HW;
#pragma unroll
            for (int i = 0; i < 16; i++) {
                float4 v0 = *(const float4*)(s0 + 4 * i);
                float4 v1 = *(const float4*)(s1 + 4 * i);
                const int px = px0 + 4 * i;
                Bsd[(px + 0) * (LSTR / 2) + c2] = (unsigned)f2bf(v0.x) | ((unsigned)f2bf(v1.x) << 16);
                Bsd[(px + 1) * (LSTR / 2) + c2] = (unsigned)f2bf(v0.y) | ((unsigned)f2bf(v1.y) << 16);
                Bsd[(px + 2) * (LSTR / 2) + c2] = (unsigned)f2bf(v0.z) | ((unsigned)f2bf(v1.z) << 16);
                Bsd[(px + 3) * (LSTR / 2) + c2] = (unsigned)f2bf(v0.w) | ((unsigned)f2bf(v1.w) << 16);
            }
        } else {
            const ushort_t* s0 = (const ushort_t*)inp + (size_t)b * BPL + (size_t)(2 * c2) * HW + hw0 + px0;
            const ushort_t* s1 = s0 + HW;
#pragma unroll
            for (int i = 0; i < 8; i++) {
                union { uint4 v; ushort_t u[8]; } r0, r1;
                r0.v = *(const uint4*)(s0 + 8 * i);
                r1.v = *(const uint4*)(s1 + 8 * i);
                const int px = px0 + 8 * i;
#pragma unroll
                for (int j = 0; j < 8; j++)
                    Bsd[(px + j) * (LSTR / 2) + c2] = (unsigned)r0.u[j] | ((unsigned)r1.u[j] << 16);
            }
        }
    }
    __syncthreads();

    const int wave = tid >> 6, lane = tid & 63, quad = lane >> 4, L = lane & 15;
    const int coutw = wave * 64;

    floatx4 acc[4][8];

    // GEMM over K=256 (8 chunks of 32): A from global in fragment-packed order
    // (each load = 1KB contiguous per wave, L2-hot, prefetched one chunk ahead),
    // B from LDS.
    auto run_gemm = [&](const ushort_t* W) {
#pragma unroll
        for (int mt = 0; mt < 4; mt++)
#pragma unroll
            for (int nt = 0; nt < 8; nt++) acc[mt][nt] = (floatx4){0.f, 0.f, 0.f, 0.f};
        const ushort_t* Ab = W + (size_t)wave * 16384 + (size_t)lane * 8;
        short8 Ac[4], An[4];
#pragma unroll
        for (int mt = 0; mt < 4; mt++) Ac[mt] = *(const short8*)(Ab + mt * 512);
#pragma unroll
        for (int kt = 0; kt < 8; kt++) {
            if (kt < 7) {
#pragma unroll
                for (int mt = 0; mt < 4; mt++)
                    An[mt] = *(const short8*)(Ab + ((kt + 1) * 4 + mt) * 512);
            }
            short8 Bf[8];
#pragma unroll
            for (int nt = 0; nt < 8; nt++)
                Bf[nt] = *(const short8*)&Bs[(nt * 16 + L) * LSTR + kt * 32 + quad * 8];
#pragma unroll
            for (int mt = 0; mt < 4; mt++)
#pragma unroll
                for (int nt = 0; nt < 8; nt++)
                    acc[mt][nt] = __builtin_amdgcn_mfma_f32_16x16x32_bf16(
                        Ac[mt], Bf[nt], acc[mt][nt], 0, 0, 0);
            if (kt < 7) {
#pragma unroll
                for (int mt = 0; mt < 4; mt++) Ac[mt] = An[mt];
            }
        }
    };

    run_gemm(wA);

    if (MODE == 0) {
        // epilogue: bnA + relu -> bf16 NCHW
        ushort_t* outb = (ushort_t*)outp + (size_t)b * BPL + hw0;
#pragma unroll
        for (int mt = 0; mt < 4; mt++) {
#pragma unroll
            for (int r = 0; r < 4; r++) {
                const int cout = coutw + mt * 16 + quad * 4 + r;
                const float s = scA[cout], h0 = shA[cout];
#pragma unroll
                for (int nt = 0; nt < 8; nt++)
                    outb[(size_t)cout * HW + nt * 16 + L] =
                        f2bf(fmaxf(fmaf(acc[mt][nt][r], s, h0), 0.f));
            }
        }
    } else {
        // t = relu(bnA(.)) -> back into Bs (in-place; s fully consumed)
        __syncthreads();
#pragma unroll
        for (int mt = 0; mt < 4; mt++) {
            const int cout0 = coutw + mt * 16 + quad * 4;
            float sc4[4], sh4[4];
#pragma unroll
            for (int r = 0; r < 4; r++) { sc4[r] = scA[cout0 + r]; sh4[r] = shA[cout0 + r]; }
#pragma unroll
            for (int nt = 0; nt < 8; nt++) {
                const int px = nt * 16 + L;
                ushort4 pk;
                pk.x = f2bf(fmaxf(fmaf(acc[mt][nt][0], sc4[0], sh4[0]), 0.f));
                pk.y = f2bf(fmaxf(fmaf(acc[mt][nt][1], sc4[1], sh4[1]), 0.f));
                pk.z = f2bf(fmaxf(fmaf(acc[mt][nt][2], sc4[2], sh4[2]), 0.f));
                pk.w = f2bf(fmaxf(fmaf(acc[mt][nt][3], sc4[3], sh4[3]), 0.f));
                *(ushort4*)&Bs[px * LSTR + cout0] = pk;
            }
        }
        __syncthreads();
        run_gemm(wB);
        // epilogue: bnB + relu -> fp32 NCHW
        float* outb = (float*)outp + (size_t)b * BPL + hw0;
#pragma unroll
        for (int mt = 0; mt < 4; mt++) {
#pragma unroll
            for (int r = 0; r < 4; r++) {
                const int cout = coutw + mt * 16 + quad * 4 + r;
                const float s = scB[cout], h0 = shB[cout];
#pragma unroll
                for (int nt = 0; nt < 8; nt++)
                    outb[(size_t)cout * HW + nt * 16 + L] =
                        fmaxf(fmaf(acc[mt][nt][r], s, h0), 0.f);
            }
        }
    }
}

// ---------------------------------------------------------------------------
// Combined 9x9 depthwise (+identity, +summed bias), bf16 NCHW in/out.
// One block per (b,c) plane. Tile stored as RAW bf16 (input is already bf16):
//  - staging is a straight copy (no convert VALU), writes are ds_write_b64
//    with (5r+4q mod 16) bank-pair tiling -> conflict-free
//  - window reads are 3x ds_read_b64/row: a quarter-wave (fixed ty, tx=0..15)
//    spans ONE contiguous 128B wrap -> conflict-free by construction
//    (b128 f32 reads had an unfixable 8-lane/16B-span alias: R1 post-mortem)
//  - LDS traffic halves (bf16 vs f32); unpack = shift/and in VALU (+12/row)
// Tile 72 rows x DSTR(84) shorts = 11.8 KB -> 8 blocks/CU (wave-limited).
__global__ __launch_bounds__(256, 3) void dw_kernel(
    const ushort_t* __restrict__ h, const float* __restrict__ WcP,
    const float* __restrict__ biasc, ushort_t* __restrict__ out)
{
    const int bcp = blockIdx.x, c = bcp & 255;
    const size_t plane = (size_t)bcp * HW;
    __shared__ __align__(16) ushort_t tile[72 * DSTR];   // 11.8 KB
    const int tid = threadIdx.x;

    // zero halo: full rows 0..3 & 68..71 (cols 4..75 used), interior rows'
    // left cols 4..7 and right cols 72..75. All 8B-aligned uint2 stores.
    for (int f = tid; f < 272; f += 256) {
        int row, col;
        if (f < 144) { int rr = f / 18; row = (rr < 4) ? rr : rr + 64; col = 4 + (f % 18) * 4; }
        else { int f2 = f - 144; row = 4 + (f2 >> 1); col = (f2 & 1) ? 72 : 4; }
        *(uint2*)&tile[row * DSTR + col] = make_uint2(0u, 0u);
    }
    // interior: thread copies 32 contiguous bytes (16 px) of input row r.
    // Global: consecutive 4 threads cover a full 128B row; wave = 2KB contiguous.
    // Interior pixels live at tile cols 8..71 (left pad keeps stores 8B-aligned).
    {
        const int r = tid >> 2, q = tid & 3;
        const ushort_t* src = h + plane + r * 64 + q * 16;
        uint4 a = *(const uint4*)src;
        uint4 b = *(const uint4*)(src + 8);
        ushort_t* drow = &tile[(r + 4) * DSTR + 8 + q * 16];
        *(uint2*)(drow + 0)  = make_uint2(a.x, a.y);
        *(uint2*)(drow + 4)  = make_uint2(a.z, a.w);
        *(uint2*)(drow + 8)  = make_uint2(b.x, b.y);
        *(uint2*)(drow + 12) = make_uint2(b.z, b.w);
    }
    __syncthreads();

    const int tx = tid & 15, ty = tid >> 4;
    const int x0 = tx * 4, y0 = ty * 4;
    float acc[4][4];
#pragma unroll
    for (int i = 0; i < 4; i++)
#pragma unroll
        for (int j = 0; j < 4; j++) acc[i][j] = 0.f;

    const float* wp = WcP + c * 128;
    float wr[48];

    // window row loader: 12 bf16 from tile cols x0+4 .. x0+15 (3x b64 + unpack)
    auto ldrow = [&](int r6, float* win) {
        const ushort_t* rp = &tile[(y0 + r6) * DSTR + x0 + 4];
        uint2 a = *(const uint2*)rp;
        uint2 b = *(const uint2*)(rp + 4);
        uint2 c2 = *(const uint2*)(rp + 8);
        up2(a.x, win + 0);  up2(a.y, win + 2);
        up2(b.x, win + 4);  up2(b.y, win + 6);
        up2(c2.x, win + 8); up2(c2.y, win + 10);
    };

    // chunk A: dy 0..4 (45 weights), rows y0+0..7
#pragma unroll
    for (int i = 0; i < 12; i++) *(float4*)&wr[4 * i] = *(const float4*)(wp + 4 * i);
#pragma unroll
    for (int r6 = 0; r6 < 8; r6++) {
        float win[12];
        ldrow(r6, win);
#pragma unroll
        for (int yy = 0; yy < 4; yy++) {
            const int d = r6 - yy;
            if (d >= 0 && d <= 4) {
#pragma unroll
                for (int t = 0; t < 9; t++)
#pragma unroll
                    for (int j = 0; j < 4; j++)
                        acc[yy][j] = fmaf(wr[d * 9 + t], win[j + t], acc[yy][j]);
            }
        }
    }
    // chunk B: dy 5..8 (36 weights), rows y0+5..11
#pragma unroll
    for (int i = 0; i < 9; i++) *(float4*)&wr[4 * i] = *(const float4*)(wp + 64 + 4 * i);
#pragma unroll
    for (int r6 = 5; r6 < 12; r6++) {
        float win[12];
        ldrow(r6, win);
#pragma unroll
        for (int yy = 0; yy < 4; yy++) {
            const int d = r6 - yy;
            if (d >= 5 && d <= 8) {
#pragma unroll
                for (int t = 0; t < 9; t++)
#pragma unroll
                    for (int j = 0; j < 4; j++)
                        acc[yy][j] = fmaf(wr[(d - 5) * 9 + t], win[j + t], acc[yy][j]);
            }
        }
    }

    const float bb = biasc[c];
#pragma unroll
    for (int yy = 0; yy < 4; yy++) {
        ushort4 o;
        o.x = f2bf(acc[yy][0] + bb);
        o.y = f2bf(acc[yy][1] + bb);
        o.z = f2bf(acc[yy][2] + bb);
        o.w = f2bf(acc[yy][3] + bb);
        *(ushort4*)&out[plane + (size_t)(y0 + yy) * 64 + x0] = o;
    }
}

// ---------------------------------------------------------------------------
extern "C" void kernel_launch(void* const* d_in, const int* in_sizes, int n_in,
                              void* d_out, int out_size, void* d_ws, size_t ws_size,
                              hipStream_t stream) {
    const float* x     = (const float*)d_in[0];
    const float* pre_w = (const float*)d_in[1];
    const float* bn1g  = (const float*)d_in[2];
    const float* bn1b  = (const float*)d_in[3];
    const float* bn1m  = (const float*)d_in[4];
    const float* bn1v  = (const float*)d_in[5];
    const float* dw3w  = (const float*)d_in[6];
    const float* dw3b  = (const float*)d_in[7];
    const float* dw5w  = (const float*)d_in[8];
    const float* dw5b  = (const float*)d_in[9];
    const float* dw7w  = (const float*)d_in[10];
    const float* dw7b  = (const float*)d_in[11];
    const float* dw9w  = (const float*)d_in[12];
    const float* dw9b  = (const float*)d_in[13];
    const float* pww   = (const float*)d_in[14];
    const float* bn2g  = (const float*)d_in[15];
    const float* bn2b  = (const float*)d_in[16];
    const float* bn2m  = (const float*)d_in[17];
    const float* bn2v  = (const float*)d_in[18];
    const float* postw = (const float*)d_in[19];
    const float* bn3g  = (const float*)d_in[20];
    const float* bn3b  = (const float*)d_in[21];
    const float* bn3m  = (const float*)d_in[22];
    const float* bn3v  = (const float*)d_in[23];

    // Buffers:
    //   h (bf16, 32 MiB)  -> d_out storage (dead before final fp32 write)
    //   s (bf16, 32 MiB)  -> ws[0:32Mi]
    //   aux               -> ws + 33 MiB
    char* wsb = (char*)d_ws;
    ushort_t* sbuf = (ushort_t*)wsb;
    ushort_t* hbuf = (ushort_t*)d_out;
    char* aux = wsb + (size_t)33 * 1024 * 1024;
    ushort_t* w1b = (ushort_t*)aux;
    ushort_t* w2b = w1b + 65536;
    ushort_t* w3b = w2b + 65536;
    float* WcP   = (float*)(w3b + 65536);      // 256*128 fp32
    float* biasc = WcP + 256 * 128;
    float* sc1 = biasc + 256;  float* sh1 = sc1 + 256;
    float* sc2 = sh1 + 256;    float* sh2 = sc2 + 256;
    float* sc3 = sh2 + 256;    float* sh3 = sc3 + 256;

    prep_kernel<<<256, 256, 0, stream>>>(
        pre_w, pww, postw,
        bn1g, bn1b, bn1m, bn1v, bn2g, bn2b, bn2m, bn2v, bn3g, bn3b, bn3m, bn3v,
        dw3w, dw3b, dw5w, dw5b, dw7w, dw7b, dw9w, dw9b,
        w1b, w2b, w3b, WcP, biasc, sc1, sh1, sc2, sh2, sc3, sh3);

    // conv1: x fp32 -> h bf16 NCHW (in d_out storage)
    conv_tile<0><<<512, 256, 0, stream>>>(x, w1b, sc1, sh1,
                                          nullptr, nullptr, nullptr, hbuf);
    // dw: h -> s bf16 NCHW (in ws)
    dw_kernel<<<16 * CCH, 256, 0, stream>>>(hbuf, WcP, biasc, sbuf);
    // conv2+conv3 fused: s -> out fp32 NCHW (d_out; h dead)
    conv_tile<1><<<512, 256, 0, stream>>>(sbuf, w2b, sc2, sh2,
                                          w3b, sc3, sh3, (float*)d_out);
}